// Round 10
// baseline (286.425 us; speedup 1.0000x reference)
//
#include <hip/hip_runtime.h>

#define N_NODES 40000
#define N_EDGES 640000
#define E_TOT   (N_EDGES + N_NODES)
#define NUM_GRAPHS 64
#define CAP_SHIFT 6                   // 64 slots per node (deg = 1+Poisson(16))

#define CVTX_BLOCKS 5000              // N*128/4 float4s / 256
#define CVTW_BLOCKS 144               // 36864 / 256
#define GEMM_BLOCKS 625

#define BINS 157                      // 256 dst-nodes per bin
#define BIN_CAP 5120                  // entries per bin region (mean 4096 + 16 sigma)
#define TBLK 4096                     // edges per binA block (16 per thread)
#define A2BLKS ((N_EDGES + TBLK - 1) / TBLK)   // 157

typedef __attribute__((ext_vector_type(8))) short bf16x8;
typedef __attribute__((ext_vector_type(4))) float f32x4;

__device__ inline float bf2f(unsigned short u) {
    union { unsigned int i; float f; } v; v.i = ((unsigned int)u) << 16; return v.f;
}
__device__ inline unsigned short f2bf(float f) {
    union { float f; unsigned int i; } v; v.f = f;
    unsigned int r = v.i + 0x7FFF + ((v.i >> 16) & 1);
    return (unsigned short)(r >> 16);
}
// fp8 e4m3fn encode: RNE, FTZ below 2^-6, clamp to 448 (max finite, m=6)
__device__ inline unsigned char f2fp8(float f) {
    union { float f; unsigned int i; } v; v.f = f;
    unsigned int s = (v.i >> 24) & 0x80u;
    unsigned int a = v.i & 0x7FFFFFFFu;
    if (a > 0x43E00000u) a = 0x43E00000u;         // clamp |x| to 448
    a += 0x7FFFFu + ((a >> 20) & 1u);             // RNE into 3-bit mantissa
    if (a < 0x3C800000u) return (unsigned char)s; // FTZ below 2^-6
    unsigned int e = (a >> 23) - 120u;            // re-bias 127->7
    unsigned int m = (a >> 20) & 7u;
    return (unsigned char)(s | (e << 3) | m);
}
// fp8 e4m3fn decode, exact incl. denormals: assemble then scale by 2^120
__device__ inline float fp82f(unsigned int u) {
    union { unsigned int i; float f; } v;
    v.i = ((u & 0x80u) << 24) | ((u & 0x7Fu) << 20);
    return v.f * 0x1p+120f;
}

// ---------------- pass A v2: counting-sort tile (one global-atomic round) ----------------

__device__ void binA2_body(int ab, const int* __restrict__ esrc,
                           const int* __restrict__ edst,
                           int* __restrict__ bin_gcnt,
                           unsigned int* __restrict__ bins) {
    __shared__ unsigned int ebuf[TBLK];   // 16 KB
    __shared__ int bcnt[BINS];
    __shared__ int scn[256];
    __shared__ int lbase[BINS];
    __shared__ int boff[BINS];
    __shared__ int gbase[BINS];
    int tid = threadIdx.x;
    for (int i = tid; i < BINS; i += 256) bcnt[i] = 0;
    __syncthreads();
    int ebase = ab * TBLK;
    int ecount = N_EDGES - ebase; if (ecount > TBLK) ecount = TBLK;
    unsigned int ent[16];
#pragma unroll
    for (int k = 0; k < 16; ++k) {
        int idx = k * 256 + tid;
        ent[k] = 0xFFFFFFFFu;             // invalid (bin byte 0xFF > 156)
        if (idx < ecount) {
            int e = ebase + idx;
            int d = edst[e], s = esrc[e];
            ent[k] = ((unsigned int)(d >> 8) << 24) |
                     ((unsigned int)(d & 255) << 16) | (unsigned int)s;
            atomicAdd(&bcnt[d >> 8], 1);
        }
    }
    __syncthreads();
    // 256-wide Hillis-Steele inclusive scan of bcnt
    scn[tid] = (tid < BINS) ? bcnt[tid] : 0;
    __syncthreads();
    for (int off = 1; off < 256; off <<= 1) {
        int u = (tid >= off) ? scn[tid - off] : 0;
        __syncthreads();
        scn[tid] += u;
        __syncthreads();
    }
    if (tid < BINS) {
        lbase[tid] = scn[tid] - bcnt[tid];   // exclusive prefix
        boff[tid] = 0;
        if (bcnt[tid]) gbase[tid] = atomicAdd(&bin_gcnt[tid], bcnt[tid]);
    }
    __syncthreads();
#pragma unroll
    for (int k = 0; k < 16; ++k) {
        unsigned int e = ent[k];
        if (e != 0xFFFFFFFFu) {
            int bin = e >> 24;
            int pos = lbase[bin] + atomicAdd(&boff[bin], 1);
            ebuf[pos] = e;
        }
    }
    __syncthreads();
    // write-out: consecutive i -> same-bin contiguous runs (coalesced)
    for (int i = tid; i < ecount; i += 256) {
        unsigned int e = ebuf[i];
        int bin = e >> 24;
        bins[bin * BIN_CAP + gbase[bin] + (i - lbase[bin])] = e & 0x00FFFFFFu;
    }
}

// ---------------- merged: binA2 || cvt (x->bf16 + W transposes) ----------------

__global__ __launch_bounds__(256) void cvt_binA_kernel(const float* __restrict__ x,
                                                       const float* __restrict__ W0,
                                                       const float* __restrict__ W1,
                                                       const float* __restrict__ W2,
                                                       unsigned short* __restrict__ Xb,
                                                       unsigned short* __restrict__ Wt0,
                                                       unsigned short* __restrict__ Wt1,
                                                       unsigned short* __restrict__ Wt2,
                                                       const int* __restrict__ esrc,
                                                       const int* __restrict__ edst,
                                                       int* __restrict__ bin_gcnt,
                                                       unsigned int* __restrict__ bins) {
    int b = blockIdx.x;
    int tid = threadIdx.x;
    if (b < A2BLKS) {
        binA2_body(b, esrc, edst, bin_gcnt, bins);
    } else if (b < A2BLKS + CVTX_BLOCKS) {
        int i = (b - A2BLKS) * 256 + tid;
        float4 v = ((const float4*)x)[i];
        ushort4 o;
        o.x = f2bf(v.x); o.y = f2bf(v.y); o.z = f2bf(v.z); o.w = f2bf(v.w);
        ((ushort4*)Xb)[i] = o;
    } else {
        int idx = (b - A2BLKS - CVTX_BLOCKS) * 256 + tid;
        if (idx < 16384) {
            int n = idx >> 7, k = idx & 127;
            Wt0[idx] = f2bf(W0[k * 128 + n]);
        } else if (idx < 32768) {
            int i = idx - 16384;
            int n = i >> 7, k = i & 127;
            Wt1[i] = f2bf(W1[k * 128 + n]);
        } else if (idx < 36864) {
            int i = idx - 32768;
            int n = i >> 7, k = i & 127;   // n in [0,32)
            Wt2[i] = f2bf(W2[k * 32 + n]);
        }
    }
}

// ---------------- pass B: bin -> padded LDS bucket tile -> coalesced psrc/cnt ----------------

__device__ void binB_body(int bb, const int* __restrict__ bin_gcnt,
                          const unsigned int* __restrict__ bins,
                          int* __restrict__ cnt,
                          unsigned short* __restrict__ psrc) {
    __shared__ unsigned short lbuck[256 * 64];   // 32 KB
    __shared__ int lcnt[256];
    int tid = threadIdx.x;
    lcnt[tid] = 0;
    __syncthreads();
    int cntE = bin_gcnt[bb];
    for (int i = tid; i < cntE; i += 256) {
        unsigned int entry = bins[bb * BIN_CAP + i];
        int dl = entry >> 16;
        int pos = atomicAdd(&lcnt[dl], 1);
        lbuck[dl * 64 + pos] = (unsigned short)(entry & 0xFFFFu);
    }
    __syncthreads();
    int node = bb * 256 + tid;
    if (node < N_NODES) {                        // self-loop appended here
        int pos = lcnt[tid];
        lbuck[tid * 64 + pos] = (unsigned short)node;
        lcnt[tid] = pos + 1;
    }
    __syncthreads();
    int base = bb * (256 * 64);
    int lim = (bb == BINS - 1) ? ((N_NODES - bb * 256) * 64) : (256 * 64);
    for (int i = tid; i < lim; i += 256)
        psrc[base + i] = lbuck[i];
    if (node < N_NODES) cnt[node] = lcnt[tid];
}

// ---------------- gemm128 body (MFMA, bf16 in, fp8 Hb out, fused attention scores) ----------------
// ALS/ALD written interleaved from EXACT f32 accumulators: ALS4[node*4 + head]

__device__ __forceinline__ void gemm128_body(int blk,
                                             const unsigned short* __restrict__ Xb,
                                             const unsigned short* __restrict__ Wt,
                                             const float* __restrict__ asrc,
                                             const float* __restrict__ adst,
                                             unsigned char* __restrict__ Hb8,
                                             float* __restrict__ ALS4,
                                             float* __restrict__ ALD4) {
    int wave = threadIdx.x >> 6;
    int lane = threadIdx.x & 63;
    int l15 = lane & 15;
    int q = lane >> 4;
    int r0 = (blk * 4 + wave) * 16;   // 625*4*16 = 40000 exact

    f32x4 acc[8];
#pragma unroll
    for (int t = 0; t < 8; ++t) acc[t] = (f32x4){0.f, 0.f, 0.f, 0.f};

    float asv[8], adv[8];
#pragma unroll
    for (int t = 0; t < 8; ++t) {
        int c = t * 16 + l15;
        asv[t] = asrc[c];
        adv[t] = adst[c];
    }

    const unsigned short* xrow = Xb + (long)(r0 + l15) * 128 + q * 8;
    const unsigned short* wrow = Wt + (long)l15 * 128 + q * 8;
#pragma unroll
    for (int kt = 0; kt < 4; ++kt) {
        bf16x8 a = *(const bf16x8*)(xrow + kt * 32);
#pragma unroll
        for (int t = 0; t < 8; ++t) {
            bf16x8 b = *(const bf16x8*)(wrow + (long)t * 16 * 128 + kt * 32);
            acc[t] = __builtin_amdgcn_mfma_f32_16x16x32_bf16(a, b, acc[t], 0, 0, 0);
        }
    }

#pragma unroll
    for (int t = 0; t < 8; ++t)
#pragma unroll
        for (int i = 0; i < 4; ++i)
            Hb8[(long)(r0 + q * 4 + i) * 128 + t * 16 + l15] = f2fp8(acc[t][i]);

#pragma unroll
    for (int i = 0; i < 4; ++i) {
        float ps0 = acc[0][i] * asv[0] + acc[1][i] * asv[1];
        float ps1 = acc[2][i] * asv[2] + acc[3][i] * asv[3];
        float ps2 = acc[4][i] * asv[4] + acc[5][i] * asv[5];
        float ps3 = acc[6][i] * asv[6] + acc[7][i] * asv[7];
        float pd0 = acc[0][i] * adv[0] + acc[1][i] * adv[1];
        float pd1 = acc[2][i] * adv[2] + acc[3][i] * adv[3];
        float pd2 = acc[4][i] * adv[4] + acc[5][i] * adv[5];
        float pd3 = acc[6][i] * adv[6] + acc[7][i] * adv[7];
#pragma unroll
        for (int m = 1; m < 16; m <<= 1) {
            ps0 += __shfl_xor(ps0, m, 16); ps1 += __shfl_xor(ps1, m, 16);
            ps2 += __shfl_xor(ps2, m, 16); ps3 += __shfl_xor(ps3, m, 16);
            pd0 += __shfl_xor(pd0, m, 16); pd1 += __shfl_xor(pd1, m, 16);
            pd2 += __shfl_xor(pd2, m, 16); pd3 += __shfl_xor(pd3, m, 16);
        }
        int r = r0 + q * 4 + i;
        if (l15 < 4) {
            float v = (l15 == 0) ? ps0 : (l15 == 1) ? ps1 : (l15 == 2) ? ps2 : ps3;
            ALS4[r * 4 + l15] = v;
        } else if (l15 < 8) {
            int h = l15 - 4;
            float v = (h == 0) ? pd0 : (h == 1) ? pd1 : (h == 2) ? pd2 : pd3;
            ALD4[r * 4 + h] = v;
        }
    }
}

// merged: binB || gemm128 layer-0 (disjoint in/out; binB blocks first)
__global__ __launch_bounds__(256) void gemm0_binB_kernel(const unsigned short* __restrict__ Xb,
                                                         const unsigned short* __restrict__ Wt,
                                                         const float* __restrict__ asrc,
                                                         const float* __restrict__ adst,
                                                         unsigned char* __restrict__ Hb8,
                                                         float* __restrict__ ALS4,
                                                         float* __restrict__ ALD4,
                                                         const int* __restrict__ bin_gcnt,
                                                         const unsigned int* __restrict__ bins,
                                                         int* __restrict__ cnt,
                                                         unsigned short* __restrict__ psrc) {
    int b = blockIdx.x;
    if (b < BINS) {
        binB_body(b, bin_gcnt, bins, cnt, psrc);
    } else {
        gemm128_body(b - BINS, Xb, Wt, asrc, adst, Hb8, ALS4, ALD4);
    }
}

__global__ __launch_bounds__(256) void gemm128_mfma(const unsigned short* __restrict__ Xb,
                                                    const unsigned short* __restrict__ Wt,
                                                    const float* __restrict__ asrc,
                                                    const float* __restrict__ adst,
                                                    unsigned char* __restrict__ Hb8,
                                                    float* __restrict__ ALS4,
                                                    float* __restrict__ ALD4) {
    gemm128_body(blockIdx.x, Xb, Wt, asrc, adst, Hb8, ALS4, ALD4);
}

// ---------------- MFMA GEMM (128 -> 32, 1 head) ---- H2b stays bf16 ----
__global__ __launch_bounds__(256) void gemm32_mfma(const unsigned short* __restrict__ Xb,
                                                   const unsigned short* __restrict__ Wt2,
                                                   const float* __restrict__ asrc,
                                                   const float* __restrict__ adst,
                                                   unsigned short* __restrict__ H2b,
                                                   float* __restrict__ ALS,
                                                   float* __restrict__ ALD) {
    int wave = threadIdx.x >> 6;
    int lane = threadIdx.x & 63;
    int l15 = lane & 15;
    int q = lane >> 4;
    int r0 = (blockIdx.x * 4 + wave) * 16;   // 625*4*16 = 40000 exact

    f32x4 acc[2];
    acc[0] = (f32x4){0.f, 0.f, 0.f, 0.f};
    acc[1] = (f32x4){0.f, 0.f, 0.f, 0.f};

    const unsigned short* xrow = Xb + (long)(r0 + l15) * 128 + q * 8;
    const unsigned short* wrow = Wt2 + (long)l15 * 128 + q * 8;
#pragma unroll
    for (int kt = 0; kt < 4; ++kt) {
        bf16x8 a = *(const bf16x8*)(xrow + kt * 32);
#pragma unroll
        for (int t = 0; t < 2; ++t) {
            bf16x8 b = *(const bf16x8*)(wrow + (long)t * 16 * 128 + kt * 32);
            acc[t] = __builtin_amdgcn_mfma_f32_16x16x32_bf16(a, b, acc[t], 0, 0, 0);
        }
    }

    float as0 = asrc[l15], as1 = asrc[16 + l15];
    float ad0 = adst[l15], ad1 = adst[16 + l15];
#pragma unroll
    for (int t = 0; t < 2; ++t)
#pragma unroll
        for (int i = 0; i < 4; ++i)
            H2b[(long)(r0 + q * 4 + i) * 32 + t * 16 + l15] = f2bf(acc[t][i]);

#pragma unroll
    for (int i = 0; i < 4; ++i) {
        float ps = acc[0][i] * as0 + acc[1][i] * as1;
        float pd = acc[0][i] * ad0 + acc[1][i] * ad1;
#pragma unroll
        for (int m = 1; m < 16; m <<= 1) {
            ps += __shfl_xor(ps, m, 16);
            pd += __shfl_xor(pd, m, 16);
        }
        if (l15 == 0) {
            int r = r0 + q * 4 + i;
            ALS[r] = ps;
            ALD[r] = pd;
        }
    }
}

// ---------------- Edge aggregation (v1 structure, fp8 Hb gathers: 2B/lane) ----------------
__global__ __launch_bounds__(256) void agg128(const unsigned char* __restrict__ Hb8,
                                              const float* __restrict__ ALS4,
                                              const float* __restrict__ ALD4,
                                              const int* __restrict__ cnt,
                                              const unsigned short* __restrict__ psrc,
                                              const float* __restrict__ bias,
                                              unsigned short* __restrict__ OUTb) {
    int n = blockIdx.x * 4 + (threadIdx.x >> 6);
    n = __builtin_amdgcn_readfirstlane(n);
    if (n >= N_NODES) return;
    int lane = threadIdx.x & 63;
    int c = lane * 2;
    int head = lane >> 4;
    int e16 = lane & 15;
    float aldh = ALD4[n * 4 + head];
    int j0 = n << CAP_SHIFT;
    int j1 = j0 + __builtin_amdgcn_readfirstlane(cnt[n]);
    float a0 = 0.f, a1 = 0.f, dsum = 0.f;
    for (int jb = j0; jb < j1; jb += 16) {
        int j = jb + e16;
        int jc = (j < j1) ? j : (j1 - 1);
        int s = (int)psrc[jc];
        float e = ALS4[s * 4 + head] + aldh;
        e = (e > 0.f) ? e : 0.2f * e;
        float w = (j < j1) ? __expf(e) : 0.f;
        int st[16]; float wt[16];
#pragma unroll
        for (int t = 0; t < 16; ++t) {
            st[t] = __shfl(s, t, 16);
            wt[t] = __shfl(w, t, 16);
        }
        unsigned short hv[16];
#pragma unroll
        for (int t = 0; t < 16; ++t)
            hv[t] = *(const unsigned short*)(Hb8 + (long)st[t] * 128 + c);
#pragma unroll
        for (int t = 0; t < 16; ++t) {
            float h0 = fp82f(hv[t] & 0xFFu);
            float h1 = fp82f((unsigned int)hv[t] >> 8);
            dsum += wt[t];
            a0 += wt[t] * h0;
            a1 += wt[t] * h1;
        }
    }
    float inv = 1.0f / dsum;
    float o0 = a0 * inv + bias[c];
    float o1 = a1 * inv + bias[c + 1];
    o0 = (o0 > 0.f) ? o0 : (__expf(o0) - 1.f);
    o1 = (o1 > 0.f) ? o1 : (__expf(o1) - 1.f);
    ushort2 ob; ob.x = f2bf(o0); ob.y = f2bf(o1);
    *(ushort2*)(OUTb + (long)n * 128 + c) = ob;
}

// 32-channel, 1-head; half-wave per node (v1 form), bf16 H2b.
__global__ __launch_bounds__(256) void agg32(const unsigned short* __restrict__ H2b,
                                             const float* __restrict__ ALS,
                                             const float* __restrict__ ALD,
                                             const int* __restrict__ cnt,
                                             const unsigned short* __restrict__ psrc,
                                             const float* __restrict__ bias,
                                             float* __restrict__ OUT) {
    int wv = blockIdx.x * 4 + (threadIdx.x >> 6);
    int lane = threadIdx.x & 63;
    int col = lane & 31;
    int half = lane >> 5;
    int e16 = lane & 15;
    int n = wv * 2 + half;
    if (n >= N_NODES) return;
    float aldn = ALD[n];
    int j0 = n << CAP_SHIFT;
    int j1 = j0 + cnt[n];
    float a = 0.f, dsum = 0.f;
    for (int jb = j0; jb < j1; jb += 16) {
        int j = jb + e16;
        int jc = (j < j1) ? j : (j1 - 1);
        int s = (int)psrc[jc];
        float e = ALS[s] + aldn;
        e = (e > 0.f) ? e : 0.2f * e;
        float w = (j < j1) ? __expf(e) : 0.f;
        int st[16]; float wt[16];
#pragma unroll
        for (int t = 0; t < 16; ++t) {
            st[t] = __shfl(s, t, 16);
            wt[t] = __shfl(w, t, 16);
        }
        unsigned short hv[16];
#pragma unroll
        for (int t = 0; t < 16; ++t)
            hv[t] = H2b[st[t] * 32 + col];
#pragma unroll
        for (int t = 0; t < 16; ++t) {
            dsum += wt[t];
            a += wt[t] * bf2f(hv[t]);
        }
    }
    float o = a / dsum + bias[col];
    o = (o > 0.f) ? o : (__expf(o) - 1.f);
    OUT[n * 32 + col] = o;
}

// ---------------- Pooling + MLP ----------------
__global__ __launch_bounds__(256) void pool_kernel(const float* __restrict__ H3,
                                                   const int* __restrict__ batch,
                                                   float* __restrict__ gsum,
                                                   float* __restrict__ gcnt) {
    const int CHUNK = 40;
    int gid = (blockIdx.x * 256 + threadIdx.x) >> 5;
    int c = threadIdx.x & 31;
    int n0 = gid * CHUNK;
    if (n0 >= N_NODES) return;
    int n1 = n0 + CHUNK;
    if (n1 > N_NODES) n1 = N_NODES;
    int cur = batch[n0];
    float acc = 0.f;
    int cnt = 0;
    for (int n = n0; n < n1; ++n) {
        int b = batch[n];
        if (b != cur) {
            atomicAdd(&gsum[cur * 32 + c], acc);
            if (c == 0) atomicAdd(&gcnt[cur], (float)cnt);
            cur = b; acc = 0.f; cnt = 0;
        }
        acc += H3[n * 32 + c];
        cnt++;
    }
    atomicAdd(&gsum[cur * 32 + c], acc);
    if (c == 0) atomicAdd(&gcnt[cur], (float)cnt);
}

__global__ __launch_bounds__(256) void mlp_kernel(const float* __restrict__ gsum,
                                                  const float* __restrict__ gcnt,
                                                  const float* __restrict__ l1w,
                                                  const float* __restrict__ l1b,
                                                  const float* __restrict__ l2w,
                                                  const float* __restrict__ l2b,
                                                  float* __restrict__ out) {
    __shared__ float g[NUM_GRAPHS * 32];
    __shared__ float t1[NUM_GRAPHS * 128];
    int tid = threadIdx.x;
    for (int i = tid; i < NUM_GRAPHS * 32; i += 256) {
        float c = gcnt[i >> 5];
        g[i] = gsum[i] / fmaxf(c, 1.0f);
    }
    __syncthreads();
    for (int i = tid; i < NUM_GRAPHS * 128; i += 256) {
        int r = i >> 7, j = i & 127;
        float a = l1b[j];
        for (int k = 0; k < 32; ++k) a += g[r * 32 + k] * l1w[k * 128 + j];
        t1[i] = fmaxf(a, 0.f);
    }
    __syncthreads();
    for (int i = tid; i < NUM_GRAPHS * 8; i += 256) {
        int r = i >> 3, j = i & 7;
        float a = l2b[j];
        for (int k = 0; k < 128; ++k) a += t1[r * 128 + k] * l2w[k * 8 + j];
        out[i] = a;
    }
}

// ---------------- host ----------------

extern "C" void kernel_launch(void* const* d_in, const int* in_sizes, int n_in,
                              void* d_out, int out_size, void* d_ws, size_t ws_size,
                              hipStream_t stream) {
    const float* x      = (const float*)d_in[0];
    const int*   eidx   = (const int*)d_in[1];
    const int*   batch  = (const int*)d_in[2];
    const float* W0     = (const float*)d_in[3];
    const float* asrc0  = (const float*)d_in[4];
    const float* adst0  = (const float*)d_in[5];
    const float* b0     = (const float*)d_in[6];
    const float* W1     = (const float*)d_in[7];
    const float* asrc1  = (const float*)d_in[8];
    const float* adst1  = (const float*)d_in[9];
    const float* b1     = (const float*)d_in[10];
    const float* W2     = (const float*)d_in[11];
    const float* asrc2  = (const float*)d_in[12];
    const float* adst2  = (const float*)d_in[13];
    const float* b2     = (const float*)d_in[14];
    const float* l1w    = (const float*)d_in[15];
    const float* l1b    = (const float*)d_in[16];
    const float* l2w    = (const float*)d_in[17];
    const float* l2b    = (const float*)d_in[18];
    float* out = (float*)d_out;

    const int* esrc = eidx;
    const int* edst = eidx + N_EDGES;

    // workspace layout
    float* ALS  = (float*)d_ws;                       // N*4 (interleaved [N][4]; layer2 uses [N])
    float* ALD  = ALS + N_NODES * 4;                  // N*4
    float* h3   = ALD + N_NODES * 4;                  // N*32
    int* cnt    = (int*)(h3 + (long)N_NODES * 32);    // N (fully written by binB)
    int* bin_gcnt = cnt + N_NODES;                    // BINS   <- zero from here
    float* gsum = (float*)(bin_gcnt + BINS);          // 64*32
    float* gcnt = gsum + NUM_GRAPHS * 32;             // 64     <- zero to here
    unsigned int* bins = (unsigned int*)(gcnt + NUM_GRAPHS);     // BINS*BIN_CAP uint (3.2 MB)
    unsigned short* psrc = (unsigned short*)(bins + (long)BINS * BIN_CAP); // N*64 ushort (5.12 MB)
    uintptr_t p = (uintptr_t)(psrc + ((long)N_NODES << CAP_SHIFT));
    p = (p + 15) & ~(uintptr_t)15;
    unsigned short* Xb   = (unsigned short*)p;              // N*128 bf16
    unsigned char*  Hb8  = (unsigned char*)(Xb + (long)N_NODES * 128);  // N*128 fp8 (region sized as before)
    unsigned short* OUTb = (unsigned short*)(Hb8 + (long)N_NODES * 256); // N*128 bf16 (Hb region keeps 2B/elem footprint)
    unsigned short* H2b  = OUTb + (long)N_NODES * 128;      // N*32 bf16
    unsigned short* Wt0  = H2b + (long)N_NODES * 32;        // 128*128 bf16
    unsigned short* Wt1  = Wt0 + 128 * 128;                 // 128*128 bf16
    unsigned short* Wt2  = Wt1 + 128 * 128;                 // 32*128 bf16

    // zero bin_gcnt/gsum/gcnt (contiguous)
    size_t zbytes = (size_t)(BINS + NUM_GRAPHS * 32 + NUM_GRAPHS) * 4;
    hipMemsetAsync(bin_gcnt, 0, zbytes, stream);

    // merged: binA2 (counting-sort tiles) || cvt
    cvt_binA_kernel<<<A2BLKS + CVTX_BLOCKS + CVTW_BLOCKS, 256, 0, stream>>>(
        x, W0, W1, W2, Xb, Wt0, Wt1, Wt2, esrc, edst, bin_gcnt, bins);

    // merged: binB (bucket build via LDS tile) || gemm128 layer-0
    gemm0_binB_kernel<<<BINS + GEMM_BLOCKS, 256, 0, stream>>>(
        Xb, Wt0, asrc0, adst0, Hb8, ALS, ALD, bin_gcnt, bins, cnt, psrc);
    agg128<<<10000, 256, 0, stream>>>(Hb8, ALS, ALD, cnt, psrc, b0, OUTb);

    // layer 1
    gemm128_mfma<<<GEMM_BLOCKS, 256, 0, stream>>>(OUTb, Wt1, asrc1, adst1, Hb8, ALS, ALD);
    agg128<<<10000, 256, 0, stream>>>(Hb8, ALS, ALD, cnt, psrc, b1, OUTb);

    // layer 2
    gemm32_mfma<<<GEMM_BLOCKS, 256, 0, stream>>>(OUTb, Wt2, asrc2, adst2, H2b, ALS, ALD);
    agg32<<<5000, 256, 0, stream>>>(H2b, ALS, ALD, cnt, psrc, b2, h3);

    // pool + MLP
    pool_kernel<<<125, 256, 0, stream>>>(h3, batch, gsum, gcnt);
    mlp_kernel<<<1, 256, 0, stream>>>(gsum, gcnt, l1w, l1b, l2w, l2b, out);
}

// Round 11
// 285.959 us; speedup vs baseline: 1.0016x; 1.0016x over previous
//
#include <hip/hip_runtime.h>

#define N_NODES 40000
#define N_EDGES 640000
#define E_TOT   (N_EDGES + N_NODES)
#define NUM_GRAPHS 64
#define CAP_SHIFT 6                   // 64 slots per node (deg = 1+Poisson(16))

#define CVTX_BLOCKS 5000              // N*128/4 float4s / 256
#define CVTW_BLOCKS 144               // 36864 / 256
#define GEMM_BLOCKS 625

#define BINS 157                      // 256 dst-nodes per bin
#define BIN_CAP 5120                  // entries per bin region (mean 4096 + 16 sigma)
#define TBLK 4096                     // edges per binA block (16 per thread)
#define A2BLKS ((N_EDGES + TBLK - 1) / TBLK)   // 157

typedef __attribute__((ext_vector_type(8))) short bf16x8;
typedef __attribute__((ext_vector_type(4))) float f32x4;

__device__ inline float bf2f(unsigned short u) {
    union { unsigned int i; float f; } v; v.i = ((unsigned int)u) << 16; return v.f;
}
__device__ inline unsigned short f2bf(float f) {
    union { float f; unsigned int i; } v; v.f = f;
    unsigned int r = v.i + 0x7FFF + ((v.i >> 16) & 1);
    return (unsigned short)(r >> 16);
}

// ---------------- pass A v2: counting-sort tile (one global-atomic round) ----------------

__device__ void binA2_body(int ab, const int* __restrict__ esrc,
                           const int* __restrict__ edst,
                           int* __restrict__ bin_gcnt,
                           unsigned int* __restrict__ bins) {
    __shared__ unsigned int ebuf[TBLK];   // 16 KB
    __shared__ int bcnt[BINS];
    __shared__ int scn[256];
    __shared__ int lbase[BINS];
    __shared__ int boff[BINS];
    __shared__ int gbase[BINS];
    int tid = threadIdx.x;
    for (int i = tid; i < BINS; i += 256) bcnt[i] = 0;
    __syncthreads();
    int ebase = ab * TBLK;
    int ecount = N_EDGES - ebase; if (ecount > TBLK) ecount = TBLK;
    unsigned int ent[16];
#pragma unroll
    for (int k = 0; k < 16; ++k) {
        int idx = k * 256 + tid;
        ent[k] = 0xFFFFFFFFu;             // invalid (bin byte 0xFF > 156)
        if (idx < ecount) {
            int e = ebase + idx;
            int d = edst[e], s = esrc[e];
            ent[k] = ((unsigned int)(d >> 8) << 24) |
                     ((unsigned int)(d & 255) << 16) | (unsigned int)s;
            atomicAdd(&bcnt[d >> 8], 1);
        }
    }
    __syncthreads();
    // 256-wide Hillis-Steele inclusive scan of bcnt
    scn[tid] = (tid < BINS) ? bcnt[tid] : 0;
    __syncthreads();
    for (int off = 1; off < 256; off <<= 1) {
        int u = (tid >= off) ? scn[tid - off] : 0;
        __syncthreads();
        scn[tid] += u;
        __syncthreads();
    }
    if (tid < BINS) {
        lbase[tid] = scn[tid] - bcnt[tid];   // exclusive prefix
        boff[tid] = 0;
        if (bcnt[tid]) gbase[tid] = atomicAdd(&bin_gcnt[tid], bcnt[tid]);
    }
    __syncthreads();
#pragma unroll
    for (int k = 0; k < 16; ++k) {
        unsigned int e = ent[k];
        if (e != 0xFFFFFFFFu) {
            int bin = e >> 24;
            int pos = lbase[bin] + atomicAdd(&boff[bin], 1);
            ebuf[pos] = e;
        }
    }
    __syncthreads();
    // write-out: consecutive i -> same-bin contiguous runs (coalesced)
    for (int i = tid; i < ecount; i += 256) {
        unsigned int e = ebuf[i];
        int bin = e >> 24;
        bins[bin * BIN_CAP + gbase[bin] + (i - lbase[bin])] = e & 0x00FFFFFFu;
    }
}

// ---------------- merged: binA2 || cvt (x->bf16 + W transposes) ----------------

__global__ __launch_bounds__(256) void cvt_binA_kernel(const float* __restrict__ x,
                                                       const float* __restrict__ W0,
                                                       const float* __restrict__ W1,
                                                       const float* __restrict__ W2,
                                                       unsigned short* __restrict__ Xb,
                                                       unsigned short* __restrict__ Wt0,
                                                       unsigned short* __restrict__ Wt1,
                                                       unsigned short* __restrict__ Wt2,
                                                       const int* __restrict__ esrc,
                                                       const int* __restrict__ edst,
                                                       int* __restrict__ bin_gcnt,
                                                       unsigned int* __restrict__ bins) {
    int b = blockIdx.x;
    int tid = threadIdx.x;
    if (b < A2BLKS) {
        binA2_body(b, esrc, edst, bin_gcnt, bins);
    } else if (b < A2BLKS + CVTX_BLOCKS) {
        int i = (b - A2BLKS) * 256 + tid;
        float4 v = ((const float4*)x)[i];
        ushort4 o;
        o.x = f2bf(v.x); o.y = f2bf(v.y); o.z = f2bf(v.z); o.w = f2bf(v.w);
        ((ushort4*)Xb)[i] = o;
    } else {
        int idx = (b - A2BLKS - CVTX_BLOCKS) * 256 + tid;
        if (idx < 16384) {
            int n = idx >> 7, k = idx & 127;
            Wt0[idx] = f2bf(W0[k * 128 + n]);
        } else if (idx < 32768) {
            int i = idx - 16384;
            int n = i >> 7, k = i & 127;
            Wt1[i] = f2bf(W1[k * 128 + n]);
        } else if (idx < 36864) {
            int i = idx - 32768;
            int n = i >> 7, k = i & 127;   // n in [0,32)
            Wt2[i] = f2bf(W2[k * 32 + n]);
        }
    }
}

// ---------------- pass B: bin -> padded LDS bucket tile -> coalesced psrc/cnt ----------------

__device__ void binB_body(int bb, const int* __restrict__ bin_gcnt,
                          const unsigned int* __restrict__ bins,
                          int* __restrict__ cnt,
                          unsigned short* __restrict__ psrc) {
    __shared__ unsigned short lbuck[256 * 64];   // 32 KB
    __shared__ int lcnt[256];
    int tid = threadIdx.x;
    lcnt[tid] = 0;
    __syncthreads();
    int cntE = bin_gcnt[bb];
    for (int i = tid; i < cntE; i += 256) {
        unsigned int entry = bins[bb * BIN_CAP + i];
        int dl = entry >> 16;
        int pos = atomicAdd(&lcnt[dl], 1);
        lbuck[dl * 64 + pos] = (unsigned short)(entry & 0xFFFFu);
    }
    __syncthreads();
    int node = bb * 256 + tid;
    if (node < N_NODES) {                        // self-loop appended here
        int pos = lcnt[tid];
        lbuck[tid * 64 + pos] = (unsigned short)node;
        lcnt[tid] = pos + 1;
    }
    __syncthreads();
    int base = bb * (256 * 64);
    int lim = (bb == BINS - 1) ? ((N_NODES - bb * 256) * 64) : (256 * 64);
    for (int i = tid; i < lim; i += 256)
        psrc[base + i] = lbuck[i];
    if (node < N_NODES) cnt[node] = lcnt[tid];
}

// ---------------- gemm128 body (MFMA, bf16, fused attention scores) ----------------
// ALS/ALD written interleaved: ALS4[node*4 + head]

__device__ __forceinline__ void gemm128_body(int blk,
                                             const unsigned short* __restrict__ Xb,
                                             const unsigned short* __restrict__ Wt,
                                             const float* __restrict__ asrc,
                                             const float* __restrict__ adst,
                                             unsigned short* __restrict__ Hb,
                                             float* __restrict__ ALS4,
                                             float* __restrict__ ALD4) {
    int wave = threadIdx.x >> 6;
    int lane = threadIdx.x & 63;
    int l15 = lane & 15;
    int q = lane >> 4;
    int r0 = (blk * 4 + wave) * 16;   // 625*4*16 = 40000 exact

    f32x4 acc[8];
#pragma unroll
    for (int t = 0; t < 8; ++t) acc[t] = (f32x4){0.f, 0.f, 0.f, 0.f};

    float asv[8], adv[8];
#pragma unroll
    for (int t = 0; t < 8; ++t) {
        int c = t * 16 + l15;
        asv[t] = asrc[c];
        adv[t] = adst[c];
    }

    const unsigned short* xrow = Xb + (long)(r0 + l15) * 128 + q * 8;
    const unsigned short* wrow = Wt + (long)l15 * 128 + q * 8;
#pragma unroll
    for (int kt = 0; kt < 4; ++kt) {
        bf16x8 a = *(const bf16x8*)(xrow + kt * 32);
#pragma unroll
        for (int t = 0; t < 8; ++t) {
            bf16x8 b = *(const bf16x8*)(wrow + (long)t * 16 * 128 + kt * 32);
            acc[t] = __builtin_amdgcn_mfma_f32_16x16x32_bf16(a, b, acc[t], 0, 0, 0);
        }
    }

#pragma unroll
    for (int t = 0; t < 8; ++t)
#pragma unroll
        for (int i = 0; i < 4; ++i)
            Hb[(long)(r0 + q * 4 + i) * 128 + t * 16 + l15] = f2bf(acc[t][i]);

#pragma unroll
    for (int i = 0; i < 4; ++i) {
        float ps0 = acc[0][i] * asv[0] + acc[1][i] * asv[1];
        float ps1 = acc[2][i] * asv[2] + acc[3][i] * asv[3];
        float ps2 = acc[4][i] * asv[4] + acc[5][i] * asv[5];
        float ps3 = acc[6][i] * asv[6] + acc[7][i] * asv[7];
        float pd0 = acc[0][i] * adv[0] + acc[1][i] * adv[1];
        float pd1 = acc[2][i] * adv[2] + acc[3][i] * adv[3];
        float pd2 = acc[4][i] * adv[4] + acc[5][i] * adv[5];
        float pd3 = acc[6][i] * adv[6] + acc[7][i] * adv[7];
#pragma unroll
        for (int m = 1; m < 16; m <<= 1) {
            ps0 += __shfl_xor(ps0, m, 16); ps1 += __shfl_xor(ps1, m, 16);
            ps2 += __shfl_xor(ps2, m, 16); ps3 += __shfl_xor(ps3, m, 16);
            pd0 += __shfl_xor(pd0, m, 16); pd1 += __shfl_xor(pd1, m, 16);
            pd2 += __shfl_xor(pd2, m, 16); pd3 += __shfl_xor(pd3, m, 16);
        }
        int r = r0 + q * 4 + i;
        if (l15 < 4) {
            float v = (l15 == 0) ? ps0 : (l15 == 1) ? ps1 : (l15 == 2) ? ps2 : ps3;
            ALS4[r * 4 + l15] = v;
        } else if (l15 < 8) {
            int h = l15 - 4;
            float v = (h == 0) ? pd0 : (h == 1) ? pd1 : (h == 2) ? pd2 : pd3;
            ALD4[r * 4 + h] = v;
        }
    }
}

// merged: binB || gemm128 layer-0 (disjoint in/out; binB blocks first)
__global__ __launch_bounds__(256) void gemm0_binB_kernel(const unsigned short* __restrict__ Xb,
                                                         const unsigned short* __restrict__ Wt,
                                                         const float* __restrict__ asrc,
                                                         const float* __restrict__ adst,
                                                         unsigned short* __restrict__ Hb,
                                                         float* __restrict__ ALS4,
                                                         float* __restrict__ ALD4,
                                                         const int* __restrict__ bin_gcnt,
                                                         const unsigned int* __restrict__ bins,
                                                         int* __restrict__ cnt,
                                                         unsigned short* __restrict__ psrc) {
    int b = blockIdx.x;
    if (b < BINS) {
        binB_body(b, bin_gcnt, bins, cnt, psrc);
    } else {
        gemm128_body(b - BINS, Xb, Wt, asrc, adst, Hb, ALS4, ALD4);
    }
}

// ---------------- FUSED: agg128(layer L) -> LDS tile -> gemm128(layer L+1) ----------------
// Block owns 64 nodes. Agg phase: wave per node x 16 iters (v1 inner loop),
// output ELU'd bf16 into XOR-swizzled LDS tile (no OUTb in HBM). Gemm phase:
// A-fragments from tile. HbOut != HbIn (ping-pong) since other blocks still
// gather from HbIn.
__global__ __launch_bounds__(256) void agg_gemm128(const unsigned short* __restrict__ HbIn,
                                                   const float* __restrict__ ALS4i,
                                                   const float* __restrict__ ALD4i,
                                                   const int* __restrict__ cnt,
                                                   const unsigned short* __restrict__ psrc,
                                                   const float* __restrict__ bias,
                                                   const unsigned short* __restrict__ Wt,
                                                   const float* __restrict__ asrc,
                                                   const float* __restrict__ adst,
                                                   unsigned short* __restrict__ HbOut,
                                                   float* __restrict__ ALS4o,
                                                   float* __restrict__ ALD4o) {
    __shared__ unsigned short tile[64 * 128];   // 16 KB
    int wv = threadIdx.x >> 6;
    int lane = threadIdx.x & 63;
    int nbase = blockIdx.x * 64;
    int c = lane * 2;
    int head = lane >> 4;
    int e16 = lane & 15;
    for (int it = 0; it < 16; ++it) {
        int n = __builtin_amdgcn_readfirstlane(nbase + it * 4 + wv);
        float aldh = ALD4i[n * 4 + head];
        int j0 = n << CAP_SHIFT;
        int j1 = j0 + __builtin_amdgcn_readfirstlane(cnt[n]);
        float a0 = 0.f, a1 = 0.f, dsum = 0.f;
        for (int jb = j0; jb < j1; jb += 16) {
            int j = jb + e16;
            int jc = (j < j1) ? j : (j1 - 1);
            int s = (int)psrc[jc];
            float e = ALS4i[s * 4 + head] + aldh;
            e = (e > 0.f) ? e : 0.2f * e;
            float w = (j < j1) ? __expf(e) : 0.f;
            int st[16]; float wt[16];
#pragma unroll
            for (int t = 0; t < 16; ++t) {
                st[t] = __shfl(s, t, 16);
                wt[t] = __shfl(w, t, 16);
            }
            unsigned int hv[16];
#pragma unroll
            for (int t = 0; t < 16; ++t)
                hv[t] = *(const unsigned int*)(HbIn + (long)st[t] * 128 + c);
#pragma unroll
            for (int t = 0; t < 16; ++t) {
                dsum += wt[t];
                a0 += wt[t] * bf2f((unsigned short)(hv[t] & 0xFFFF));
                a1 += wt[t] * bf2f((unsigned short)(hv[t] >> 16));
            }
        }
        float inv = 1.0f / dsum;
        float o0 = a0 * inv + bias[c];
        float o1 = a1 * inv + bias[c + 1];
        o0 = (o0 > 0.f) ? o0 : (__expf(o0) - 1.f);
        o1 = (o1 > 0.f) ? o1 : (__expf(o1) - 1.f);
        int row = it * 4 + wv;
        int col = c ^ ((row & 7) << 3);     // elem-index XOR swizzle (bits 3-5)
        ushort2 ob; ob.x = f2bf(o0); ob.y = f2bf(o1);
        *(ushort2*)&tile[row * 128 + col] = ob;
    }
    __syncthreads();
    // ---- gemm phase: rows nbase + wv*16 .. +15, A from tile ----
    int l15 = lane & 15;
    int q = lane >> 4;
    f32x4 acc[8];
#pragma unroll
    for (int t = 0; t < 8; ++t) acc[t] = (f32x4){0.f, 0.f, 0.f, 0.f};
    float asv[8], adv[8];
#pragma unroll
    for (int t = 0; t < 8; ++t) {
        asv[t] = asrc[t * 16 + l15];
        adv[t] = adst[t * 16 + l15];
    }
    int row = wv * 16 + l15;
    const unsigned short* wrow = Wt + (long)l15 * 128 + q * 8;
#pragma unroll
    for (int kt = 0; kt < 4; ++kt) {
        int e0 = (q * 8 + kt * 32) ^ ((row & 7) << 3);
        bf16x8 a = *(const bf16x8*)&tile[row * 128 + e0];
#pragma unroll
        for (int t = 0; t < 8; ++t) {
            bf16x8 b = *(const bf16x8*)(wrow + (long)t * 16 * 128 + kt * 32);
            acc[t] = __builtin_amdgcn_mfma_f32_16x16x32_bf16(a, b, acc[t], 0, 0, 0);
        }
    }
    int r0 = nbase + wv * 16;
#pragma unroll
    for (int t = 0; t < 8; ++t)
#pragma unroll
        for (int i = 0; i < 4; ++i)
            HbOut[(long)(r0 + q * 4 + i) * 128 + t * 16 + l15] = f2bf(acc[t][i]);
#pragma unroll
    for (int i = 0; i < 4; ++i) {
        float ps0 = acc[0][i] * asv[0] + acc[1][i] * asv[1];
        float ps1 = acc[2][i] * asv[2] + acc[3][i] * asv[3];
        float ps2 = acc[4][i] * asv[4] + acc[5][i] * asv[5];
        float ps3 = acc[6][i] * asv[6] + acc[7][i] * asv[7];
        float pd0 = acc[0][i] * adv[0] + acc[1][i] * adv[1];
        float pd1 = acc[2][i] * adv[2] + acc[3][i] * adv[3];
        float pd2 = acc[4][i] * adv[4] + acc[5][i] * adv[5];
        float pd3 = acc[6][i] * adv[6] + acc[7][i] * adv[7];
#pragma unroll
        for (int m = 1; m < 16; m <<= 1) {
            ps0 += __shfl_xor(ps0, m, 16); ps1 += __shfl_xor(ps1, m, 16);
            ps2 += __shfl_xor(ps2, m, 16); ps3 += __shfl_xor(ps3, m, 16);
            pd0 += __shfl_xor(pd0, m, 16); pd1 += __shfl_xor(pd1, m, 16);
            pd2 += __shfl_xor(pd2, m, 16); pd3 += __shfl_xor(pd3, m, 16);
        }
        int r = r0 + q * 4 + i;
        if (l15 < 4) {
            float v = (l15 == 0) ? ps0 : (l15 == 1) ? ps1 : (l15 == 2) ? ps2 : ps3;
            ALS4o[r * 4 + l15] = v;
        } else if (l15 < 8) {
            int h = l15 - 4;
            float v = (h == 0) ? pd0 : (h == 1) ? pd1 : (h == 2) ? pd2 : pd3;
            ALD4o[r * 4 + h] = v;
        }
    }
}

// ---------------- FUSED: agg128(layer 1) -> LDS tile -> gemm32(layer 2) ----------------
__global__ __launch_bounds__(256) void agg_gemm32(const unsigned short* __restrict__ HbIn,
                                                  const float* __restrict__ ALS4i,
                                                  const float* __restrict__ ALD4i,
                                                  const int* __restrict__ cnt,
                                                  const unsigned short* __restrict__ psrc,
                                                  const float* __restrict__ bias,
                                                  const unsigned short* __restrict__ Wt2,
                                                  const float* __restrict__ asrc,
                                                  const float* __restrict__ adst,
                                                  unsigned short* __restrict__ H2b,
                                                  float* __restrict__ ALS,
                                                  float* __restrict__ ALD) {
    __shared__ unsigned short tile[64 * 128];   // 16 KB
    int wv = threadIdx.x >> 6;
    int lane = threadIdx.x & 63;
    int nbase = blockIdx.x * 64;
    int c = lane * 2;
    int head = lane >> 4;
    int e16 = lane & 15;
    for (int it = 0; it < 16; ++it) {
        int n = __builtin_amdgcn_readfirstlane(nbase + it * 4 + wv);
        float aldh = ALD4i[n * 4 + head];
        int j0 = n << CAP_SHIFT;
        int j1 = j0 + __builtin_amdgcn_readfirstlane(cnt[n]);
        float a0 = 0.f, a1 = 0.f, dsum = 0.f;
        for (int jb = j0; jb < j1; jb += 16) {
            int j = jb + e16;
            int jc = (j < j1) ? j : (j1 - 1);
            int s = (int)psrc[jc];
            float e = ALS4i[s * 4 + head] + aldh;
            e = (e > 0.f) ? e : 0.2f * e;
            float w = (j < j1) ? __expf(e) : 0.f;
            int st[16]; float wt[16];
#pragma unroll
            for (int t = 0; t < 16; ++t) {
                st[t] = __shfl(s, t, 16);
                wt[t] = __shfl(w, t, 16);
            }
            unsigned int hv[16];
#pragma unroll
            for (int t = 0; t < 16; ++t)
                hv[t] = *(const unsigned int*)(HbIn + (long)st[t] * 128 + c);
#pragma unroll
            for (int t = 0; t < 16; ++t) {
                dsum += wt[t];
                a0 += wt[t] * bf2f((unsigned short)(hv[t] & 0xFFFF));
                a1 += wt[t] * bf2f((unsigned short)(hv[t] >> 16));
            }
        }
        float inv = 1.0f / dsum;
        float o0 = a0 * inv + bias[c];
        float o1 = a1 * inv + bias[c + 1];
        o0 = (o0 > 0.f) ? o0 : (__expf(o0) - 1.f);
        o1 = (o1 > 0.f) ? o1 : (__expf(o1) - 1.f);
        int row = it * 4 + wv;
        int col = c ^ ((row & 7) << 3);
        ushort2 ob; ob.x = f2bf(o0); ob.y = f2bf(o1);
        *(ushort2*)&tile[row * 128 + col] = ob;
    }
    __syncthreads();
    // ---- gemm32 phase: rows nbase + wv*16 .. +15, A from tile ----
    int l15 = lane & 15;
    int q = lane >> 4;
    f32x4 acc[2];
    acc[0] = (f32x4){0.f, 0.f, 0.f, 0.f};
    acc[1] = (f32x4){0.f, 0.f, 0.f, 0.f};
    int row = wv * 16 + l15;
    const unsigned short* wrow = Wt2 + (long)l15 * 128 + q * 8;
#pragma unroll
    for (int kt = 0; kt < 4; ++kt) {
        int e0 = (q * 8 + kt * 32) ^ ((row & 7) << 3);
        bf16x8 a = *(const bf16x8*)&tile[row * 128 + e0];
#pragma unroll
        for (int t = 0; t < 2; ++t) {
            bf16x8 b = *(const bf16x8*)(wrow + (long)t * 16 * 128 + kt * 32);
            acc[t] = __builtin_amdgcn_mfma_f32_16x16x32_bf16(a, b, acc[t], 0, 0, 0);
        }
    }
    float as0 = asrc[l15], as1 = asrc[16 + l15];
    float ad0 = adst[l15], ad1 = adst[16 + l15];
    int r0 = nbase + wv * 16;
#pragma unroll
    for (int t = 0; t < 2; ++t)
#pragma unroll
        for (int i = 0; i < 4; ++i)
            H2b[(long)(r0 + q * 4 + i) * 32 + t * 16 + l15] = f2bf(acc[t][i]);
#pragma unroll
    for (int i = 0; i < 4; ++i) {
        float ps = acc[0][i] * as0 + acc[1][i] * as1;
        float pd = acc[0][i] * ad0 + acc[1][i] * ad1;
#pragma unroll
        for (int m = 1; m < 16; m <<= 1) {
            ps += __shfl_xor(ps, m, 16);
            pd += __shfl_xor(pd, m, 16);
        }
        if (l15 == 0) {
            int r = r0 + q * 4 + i;
            ALS[r] = ps;
            ALD[r] = pd;
        }
    }
}

// 32-channel, 1-head; half-wave per node, padded buckets (v1 form).
__global__ __launch_bounds__(256) void agg32(const unsigned short* __restrict__ H2b,
                                             const float* __restrict__ ALS,
                                             const float* __restrict__ ALD,
                                             const int* __restrict__ cnt,
                                             const unsigned short* __restrict__ psrc,
                                             const float* __restrict__ bias,
                                             float* __restrict__ OUT) {
    int wv = blockIdx.x * 4 + (threadIdx.x >> 6);
    int lane = threadIdx.x & 63;
    int col = lane & 31;
    int half = lane >> 5;
    int e16 = lane & 15;
    int n = wv * 2 + half;
    if (n >= N_NODES) return;
    float aldn = ALD[n];
    int j0 = n << CAP_SHIFT;
    int j1 = j0 + cnt[n];
    float a = 0.f, dsum = 0.f;
    for (int jb = j0; jb < j1; jb += 16) {
        int j = jb + e16;
        int jc = (j < j1) ? j : (j1 - 1);
        int s = (int)psrc[jc];
        float e = ALS[s] + aldn;
        e = (e > 0.f) ? e : 0.2f * e;
        float w = (j < j1) ? __expf(e) : 0.f;
        int st[16]; float wt[16];
#pragma unroll
        for (int t = 0; t < 16; ++t) {
            st[t] = __shfl(s, t, 16);
            wt[t] = __shfl(w, t, 16);
        }
        unsigned short hv[16];
#pragma unroll
        for (int t = 0; t < 16; ++t)
            hv[t] = H2b[st[t] * 32 + col];
#pragma unroll
        for (int t = 0; t < 16; ++t) {
            dsum += wt[t];
            a += wt[t] * bf2f(hv[t]);
        }
    }
    float o = a / dsum + bias[col];
    o = (o > 0.f) ? o : (__expf(o) - 1.f);
    OUT[n * 32 + col] = o;
}

// ---------------- Pooling + MLP ----------------
__global__ __launch_bounds__(256) void pool_kernel(const float* __restrict__ H3,
                                                   const int* __restrict__ batch,
                                                   float* __restrict__ gsum,
                                                   float* __restrict__ gcnt) {
    const int CHUNK = 40;
    int gid = (blockIdx.x * 256 + threadIdx.x) >> 5;
    int c = threadIdx.x & 31;
    int n0 = gid * CHUNK;
    if (n0 >= N_NODES) return;
    int n1 = n0 + CHUNK;
    if (n1 > N_NODES) n1 = N_NODES;
    int cur = batch[n0];
    float acc = 0.f;
    int cnt = 0;
    for (int n = n0; n < n1; ++n) {
        int b = batch[n];
        if (b != cur) {
            atomicAdd(&gsum[cur * 32 + c], acc);
            if (c == 0) atomicAdd(&gcnt[cur], (float)cnt);
            cur = b; acc = 0.f; cnt = 0;
        }
        acc += H3[n * 32 + c];
        cnt++;
    }
    atomicAdd(&gsum[cur * 32 + c], acc);
    if (c == 0) atomicAdd(&gcnt[cur], (float)cnt);
}

__global__ __launch_bounds__(256) void mlp_kernel(const float* __restrict__ gsum,
                                                  const float* __restrict__ gcnt,
                                                  const float* __restrict__ l1w,
                                                  const float* __restrict__ l1b,
                                                  const float* __restrict__ l2w,
                                                  const float* __restrict__ l2b,
                                                  float* __restrict__ out) {
    __shared__ float g[NUM_GRAPHS * 32];
    __shared__ float t1[NUM_GRAPHS * 128];
    int tid = threadIdx.x;
    for (int i = tid; i < NUM_GRAPHS * 32; i += 256) {
        float c = gcnt[i >> 5];
        g[i] = gsum[i] / fmaxf(c, 1.0f);
    }
    __syncthreads();
    for (int i = tid; i < NUM_GRAPHS * 128; i += 256) {
        int r = i >> 7, j = i & 127;
        float a = l1b[j];
        for (int k = 0; k < 32; ++k) a += g[r * 32 + k] * l1w[k * 128 + j];
        t1[i] = fmaxf(a, 0.f);
    }
    __syncthreads();
    for (int i = tid; i < NUM_GRAPHS * 8; i += 256) {
        int r = i >> 3, j = i & 7;
        float a = l2b[j];
        for (int k = 0; k < 128; ++k) a += t1[r * 128 + k] * l2w[k * 8 + j];
        out[i] = a;
    }
}

// ---------------- host ----------------

extern "C" void kernel_launch(void* const* d_in, const int* in_sizes, int n_in,
                              void* d_out, int out_size, void* d_ws, size_t ws_size,
                              hipStream_t stream) {
    const float* x      = (const float*)d_in[0];
    const int*   eidx   = (const int*)d_in[1];
    const int*   batch  = (const int*)d_in[2];
    const float* W0     = (const float*)d_in[3];
    const float* asrc0  = (const float*)d_in[4];
    const float* adst0  = (const float*)d_in[5];
    const float* b0     = (const float*)d_in[6];
    const float* W1     = (const float*)d_in[7];
    const float* asrc1  = (const float*)d_in[8];
    const float* adst1  = (const float*)d_in[9];
    const float* b1     = (const float*)d_in[10];
    const float* W2     = (const float*)d_in[11];
    const float* asrc2  = (const float*)d_in[12];
    const float* adst2  = (const float*)d_in[13];
    const float* b2     = (const float*)d_in[14];
    const float* l1w    = (const float*)d_in[15];
    const float* l1b    = (const float*)d_in[16];
    const float* l2w    = (const float*)d_in[17];
    const float* l2b    = (const float*)d_in[18];
    float* out = (float*)d_out;

    const int* esrc = eidx;
    const int* edst = eidx + N_EDGES;

    // workspace layout
    float* ALS0 = (float*)d_ws;                       // N*4 interleaved [N][4]
    float* ALD0 = ALS0 + N_NODES * 4;                 // N*4
    float* ALS1 = ALD0 + N_NODES * 4;                 // N*4
    float* ALD1 = ALS1 + N_NODES * 4;                 // N*4
    float* ALS2 = ALD1 + N_NODES * 4;                 // N
    float* ALD2 = ALS2 + N_NODES;                     // N
    float* h3   = ALD2 + N_NODES;                     // N*32
    int* cnt    = (int*)(h3 + (long)N_NODES * 32);    // N (fully written by binB)
    int* bin_gcnt = cnt + N_NODES;                    // BINS   <- zero from here
    float* gsum = (float*)(bin_gcnt + BINS);          // 64*32
    float* gcnt = gsum + NUM_GRAPHS * 32;             // 64     <- zero to here
    unsigned int* bins = (unsigned int*)(gcnt + NUM_GRAPHS);     // BINS*BIN_CAP uint (3.2 MB)
    unsigned short* psrc = (unsigned short*)(bins + (long)BINS * BIN_CAP); // N*64 ushort (5.12 MB)
    uintptr_t p = (uintptr_t)(psrc + ((long)N_NODES << CAP_SHIFT));
    p = (p + 15) & ~(uintptr_t)15;
    unsigned short* Xb   = (unsigned short*)p;              // N*128 bf16
    unsigned short* Hb0  = Xb + (long)N_NODES * 128;        // N*128 bf16 (layer-0 features)
    unsigned short* Hb1  = Hb0 + (long)N_NODES * 128;       // N*128 bf16 (layer-1 features)
    unsigned short* H2b  = Hb1 + (long)N_NODES * 128;       // N*32 bf16
    unsigned short* Wt0  = H2b + (long)N_NODES * 32;        // 128*128 bf16
    unsigned short* Wt1  = Wt0 + 128 * 128;                 // 128*128 bf16
    unsigned short* Wt2  = Wt1 + 128 * 128;                 // 32*128 bf16

    // zero bin_gcnt/gsum/gcnt (contiguous)
    size_t zbytes = (size_t)(BINS + NUM_GRAPHS * 32 + NUM_GRAPHS) * 4;
    hipMemsetAsync(bin_gcnt, 0, zbytes, stream);

    // merged: binA2 (counting-sort tiles) || cvt
    cvt_binA_kernel<<<A2BLKS + CVTX_BLOCKS + CVTW_BLOCKS, 256, 0, stream>>>(
        x, W0, W1, W2, Xb, Wt0, Wt1, Wt2, esrc, edst, bin_gcnt, bins);

    // merged: binB (bucket build via LDS tile) || gemm128 layer-0
    gemm0_binB_kernel<<<BINS + GEMM_BLOCKS, 256, 0, stream>>>(
        Xb, Wt0, asrc0, adst0, Hb0, ALS0, ALD0, bin_gcnt, bins, cnt, psrc);

    // fused: agg(layer0) -> LDS -> gemm(layer1)
    agg_gemm128<<<GEMM_BLOCKS, 256, 0, stream>>>(
        Hb0, ALS0, ALD0, cnt, psrc, b0, Wt1, asrc1, adst1, Hb1, ALS1, ALD1);

    // fused: agg(layer1) -> LDS -> gemm32(layer2)
    agg_gemm32<<<GEMM_BLOCKS, 256, 0, stream>>>(
        Hb1, ALS1, ALD1, cnt, psrc, b1, Wt2, asrc2, adst2, H2b, ALS2, ALD2);

    // layer-2 aggregation
    agg32<<<5000, 256, 0, stream>>>(H2b, ALS2, ALD2, cnt, psrc, b2, h3);

    // pool + MLP
    pool_kernel<<<125, 256, 0, stream>>>(h3, batch, gsum, gcnt);
    mlp_kernel<<<1, 256, 0, stream>>>(gsum, gcnt, l1w, l1b, l2w, l2b, out);
}

// Round 13
// 271.674 us; speedup vs baseline: 1.0543x; 1.0526x over previous
//
#include <hip/hip_runtime.h>

#define N_NODES 40000
#define N_EDGES 640000
#define E_TOT   (N_EDGES + N_NODES)
#define NUM_GRAPHS 64
#define CAP_SHIFT 6                   // 64 slots per node (deg = 1+Poisson(16))

#define CVTX_BLOCKS 5000              // N*128/4 float4s / 256
#define CVTW_BLOCKS 144               // 36864 / 256
#define GEMM_BLOCKS 625

#define BINS 157                      // 256 dst-nodes per bin
#define BIN_CAP 5120                  // entries per bin region (mean 4096 + 16 sigma)
#define TBLK 4096                     // edges per binA block (16 per thread)
#define A2BLKS ((N_EDGES + TBLK - 1) / TBLK)   // 157

typedef __attribute__((ext_vector_type(8))) short bf16x8;
typedef __attribute__((ext_vector_type(4))) float f32x4;

__device__ inline float bf2f(unsigned short u) {
    union { unsigned int i; float f; } v; v.i = ((unsigned int)u) << 16; return v.f;
}
__device__ inline unsigned short f2bf(float f) {
    union { float f; unsigned int i; } v; v.f = f;
    unsigned int r = v.i + 0x7FFF + ((v.i >> 16) & 1);
    return (unsigned short)(r >> 16);
}

// ---------------- pass A v2: counting-sort tile (one global-atomic round) ----------------

__device__ void binA2_body(int ab, const int* __restrict__ esrc,
                           const int* __restrict__ edst,
                           int* __restrict__ bin_gcnt,
                           unsigned int* __restrict__ bins) {
    __shared__ unsigned int ebuf[TBLK];   // 16 KB
    __shared__ int bcnt[BINS];
    __shared__ int scn[256];
    __shared__ int lbase[BINS];
    __shared__ int boff[BINS];
    __shared__ int gbase[BINS];
    int tid = threadIdx.x;
    for (int i = tid; i < BINS; i += 256) bcnt[i] = 0;
    __syncthreads();
    int ebase = ab * TBLK;
    int ecount = N_EDGES - ebase; if (ecount > TBLK) ecount = TBLK;
    unsigned int ent[16];
#pragma unroll
    for (int k = 0; k < 16; ++k) {
        int idx = k * 256 + tid;
        ent[k] = 0xFFFFFFFFu;             // invalid (bin byte 0xFF > 156)
        if (idx < ecount) {
            int e = ebase + idx;
            int d = edst[e], s = esrc[e];
            ent[k] = ((unsigned int)(d >> 8) << 24) |
                     ((unsigned int)(d & 255) << 16) | (unsigned int)s;
            atomicAdd(&bcnt[d >> 8], 1);
        }
    }
    __syncthreads();
    // 256-wide Hillis-Steele inclusive scan of bcnt
    scn[tid] = (tid < BINS) ? bcnt[tid] : 0;
    __syncthreads();
    for (int off = 1; off < 256; off <<= 1) {
        int u = (tid >= off) ? scn[tid - off] : 0;
        __syncthreads();
        scn[tid] += u;
        __syncthreads();
    }
    if (tid < BINS) {
        lbase[tid] = scn[tid] - bcnt[tid];   // exclusive prefix
        boff[tid] = 0;
        if (bcnt[tid]) gbase[tid] = atomicAdd(&bin_gcnt[tid], bcnt[tid]);
    }
    __syncthreads();
#pragma unroll
    for (int k = 0; k < 16; ++k) {
        unsigned int e = ent[k];
        if (e != 0xFFFFFFFFu) {
            int bin = e >> 24;
            int pos = lbase[bin] + atomicAdd(&boff[bin], 1);
            ebuf[pos] = e;
        }
    }
    __syncthreads();
    // write-out: consecutive i -> same-bin contiguous runs (coalesced)
    for (int i = tid; i < ecount; i += 256) {
        unsigned int e = ebuf[i];
        int bin = e >> 24;
        bins[bin * BIN_CAP + gbase[bin] + (i - lbase[bin])] = e & 0x00FFFFFFu;
    }
}

// ---------------- merged: binA2 || cvt (x->bf16 + W transposes) ----------------

__global__ __launch_bounds__(256) void cvt_binA_kernel(const float* __restrict__ x,
                                                       const float* __restrict__ W0,
                                                       const float* __restrict__ W1,
                                                       const float* __restrict__ W2,
                                                       unsigned short* __restrict__ Xb,
                                                       unsigned short* __restrict__ Wt0,
                                                       unsigned short* __restrict__ Wt1,
                                                       unsigned short* __restrict__ Wt2,
                                                       const int* __restrict__ esrc,
                                                       const int* __restrict__ edst,
                                                       int* __restrict__ bin_gcnt,
                                                       unsigned int* __restrict__ bins) {
    int b = blockIdx.x;
    int tid = threadIdx.x;
    if (b < A2BLKS) {
        binA2_body(b, esrc, edst, bin_gcnt, bins);
    } else if (b < A2BLKS + CVTX_BLOCKS) {
        int i = (b - A2BLKS) * 256 + tid;
        float4 v = ((const float4*)x)[i];
        ushort4 o;
        o.x = f2bf(v.x); o.y = f2bf(v.y); o.z = f2bf(v.z); o.w = f2bf(v.w);
        ((ushort4*)Xb)[i] = o;
    } else {
        int idx = (b - A2BLKS - CVTX_BLOCKS) * 256 + tid;
        if (idx < 16384) {
            int n = idx >> 7, k = idx & 127;
            Wt0[idx] = f2bf(W0[k * 128 + n]);
        } else if (idx < 32768) {
            int i = idx - 16384;
            int n = i >> 7, k = i & 127;
            Wt1[i] = f2bf(W1[k * 128 + n]);
        } else if (idx < 36864) {
            int i = idx - 32768;
            int n = i >> 7, k = i & 127;   // n in [0,32)
            Wt2[i] = f2bf(W2[k * 32 + n]);
        }
    }
}

// ---------------- pass B: bin -> padded LDS bucket tile -> coalesced psrc/cnt ----------------

__device__ void binB_body(int bb, const int* __restrict__ bin_gcnt,
                          const unsigned int* __restrict__ bins,
                          int* __restrict__ cnt,
                          unsigned short* __restrict__ psrc) {
    __shared__ unsigned short lbuck[256 * 64];   // 32 KB
    __shared__ int lcnt[256];
    int tid = threadIdx.x;
    lcnt[tid] = 0;
    __syncthreads();
    int cntE = bin_gcnt[bb];
    for (int i = tid; i < cntE; i += 256) {
        unsigned int entry = bins[bb * BIN_CAP + i];
        int dl = entry >> 16;
        int pos = atomicAdd(&lcnt[dl], 1);
        lbuck[dl * 64 + pos] = (unsigned short)(entry & 0xFFFFu);
    }
    __syncthreads();
    int node = bb * 256 + tid;
    if (node < N_NODES) {                        // self-loop appended here
        int pos = lcnt[tid];
        lbuck[tid * 64 + pos] = (unsigned short)node;
        lcnt[tid] = pos + 1;
    }
    __syncthreads();
    int base = bb * (256 * 64);
    int lim = (bb == BINS - 1) ? ((N_NODES - bb * 256) * 64) : (256 * 64);
    for (int i = tid; i < lim; i += 256)
        psrc[base + i] = lbuck[i];
    if (node < N_NODES) cnt[node] = lcnt[tid];
}

// ---------------- gemm128 body (MFMA, bf16, fused attention scores) ----------------
// ALS/ALD written interleaved: ALS4[node*4 + head]

__device__ __forceinline__ void gemm128_body(int blk,
                                             const unsigned short* __restrict__ Xb,
                                             const unsigned short* __restrict__ Wt,
                                             const float* __restrict__ asrc,
                                             const float* __restrict__ adst,
                                             unsigned short* __restrict__ Hb,
                                             float* __restrict__ ALS4,
                                             float* __restrict__ ALD4) {
    int wave = threadIdx.x >> 6;
    int lane = threadIdx.x & 63;
    int l15 = lane & 15;
    int q = lane >> 4;
    int r0 = (blk * 4 + wave) * 16;   // 625*4*16 = 40000 exact

    f32x4 acc[8];
#pragma unroll
    for (int t = 0; t < 8; ++t) acc[t] = (f32x4){0.f, 0.f, 0.f, 0.f};

    float asv[8], adv[8];
#pragma unroll
    for (int t = 0; t < 8; ++t) {
        int c = t * 16 + l15;
        asv[t] = asrc[c];
        adv[t] = adst[c];
    }

    const unsigned short* xrow = Xb + (long)(r0 + l15) * 128 + q * 8;
    const unsigned short* wrow = Wt + (long)l15 * 128 + q * 8;
#pragma unroll
    for (int kt = 0; kt < 4; ++kt) {
        bf16x8 a = *(const bf16x8*)(xrow + kt * 32);
#pragma unroll
        for (int t = 0; t < 8; ++t) {
            bf16x8 b = *(const bf16x8*)(wrow + (long)t * 16 * 128 + kt * 32);
            acc[t] = __builtin_amdgcn_mfma_f32_16x16x32_bf16(a, b, acc[t], 0, 0, 0);
        }
    }

#pragma unroll
    for (int t = 0; t < 8; ++t)
#pragma unroll
        for (int i = 0; i < 4; ++i)
            Hb[(long)(r0 + q * 4 + i) * 128 + t * 16 + l15] = f2bf(acc[t][i]);

#pragma unroll
    for (int i = 0; i < 4; ++i) {
        float ps0 = acc[0][i] * asv[0] + acc[1][i] * asv[1];
        float ps1 = acc[2][i] * asv[2] + acc[3][i] * asv[3];
        float ps2 = acc[4][i] * asv[4] + acc[5][i] * asv[5];
        float ps3 = acc[6][i] * asv[6] + acc[7][i] * asv[7];
        float pd0 = acc[0][i] * adv[0] + acc[1][i] * adv[1];
        float pd1 = acc[2][i] * adv[2] + acc[3][i] * adv[3];
        float pd2 = acc[4][i] * adv[4] + acc[5][i] * adv[5];
        float pd3 = acc[6][i] * adv[6] + acc[7][i] * adv[7];
#pragma unroll
        for (int m = 1; m < 16; m <<= 1) {
            ps0 += __shfl_xor(ps0, m, 16); ps1 += __shfl_xor(ps1, m, 16);
            ps2 += __shfl_xor(ps2, m, 16); ps3 += __shfl_xor(ps3, m, 16);
            pd0 += __shfl_xor(pd0, m, 16); pd1 += __shfl_xor(pd1, m, 16);
            pd2 += __shfl_xor(pd2, m, 16); pd3 += __shfl_xor(pd3, m, 16);
        }
        int r = r0 + q * 4 + i;
        if (l15 < 4) {
            float v = (l15 == 0) ? ps0 : (l15 == 1) ? ps1 : (l15 == 2) ? ps2 : ps3;
            ALS4[r * 4 + l15] = v;
        } else if (l15 < 8) {
            int h = l15 - 4;
            float v = (h == 0) ? pd0 : (h == 1) ? pd1 : (h == 2) ? pd2 : pd3;
            ALD4[r * 4 + h] = v;
        }
    }
}

// merged: binB || gemm128 layer-0 (disjoint in/out; binB blocks first)
__global__ __launch_bounds__(256) void gemm0_binB_kernel(const unsigned short* __restrict__ Xb,
                                                         const unsigned short* __restrict__ Wt,
                                                         const float* __restrict__ asrc,
                                                         const float* __restrict__ adst,
                                                         unsigned short* __restrict__ Hb,
                                                         float* __restrict__ ALS4,
                                                         float* __restrict__ ALD4,
                                                         const int* __restrict__ bin_gcnt,
                                                         const unsigned int* __restrict__ bins,
                                                         int* __restrict__ cnt,
                                                         unsigned short* __restrict__ psrc) {
    int b = blockIdx.x;
    if (b < BINS) {
        binB_body(b, bin_gcnt, bins, cnt, psrc);
    } else {
        gemm128_body(b - BINS, Xb, Wt, asrc, adst, Hb, ALS4, ALD4);
    }
}

__global__ __launch_bounds__(256) void gemm128_mfma(const unsigned short* __restrict__ Xb,
                                                    const unsigned short* __restrict__ Wt,
                                                    const float* __restrict__ asrc,
                                                    const float* __restrict__ adst,
                                                    unsigned short* __restrict__ Hb,
                                                    float* __restrict__ ALS4,
                                                    float* __restrict__ ALD4) {
    gemm128_body(blockIdx.x, Xb, Wt, asrc, adst, Hb, ALS4, ALD4);
}

// ---------------- MFMA GEMM (128 -> 32, 1 head) ----------------
__global__ __launch_bounds__(256) void gemm32_mfma(const unsigned short* __restrict__ Xb,
                                                   const unsigned short* __restrict__ Wt2,
                                                   const float* __restrict__ asrc,
                                                   const float* __restrict__ adst,
                                                   unsigned short* __restrict__ H2b,
                                                   float* __restrict__ ALS,
                                                   float* __restrict__ ALD) {
    int wave = threadIdx.x >> 6;
    int lane = threadIdx.x & 63;
    int l15 = lane & 15;
    int q = lane >> 4;
    int r0 = (blockIdx.x * 4 + wave) * 16;   // 625*4*16 = 40000 exact

    f32x4 acc[2];
    acc[0] = (f32x4){0.f, 0.f, 0.f, 0.f};
    acc[1] = (f32x4){0.f, 0.f, 0.f, 0.f};

    const unsigned short* xrow = Xb + (long)(r0 + l15) * 128 + q * 8;
    const unsigned short* wrow = Wt2 + (long)l15 * 128 + q * 8;
#pragma unroll
    for (int kt = 0; kt < 4; ++kt) {
        bf16x8 a = *(const bf16x8*)(xrow + kt * 32);
#pragma unroll
        for (int t = 0; t < 2; ++t) {
            bf16x8 b = *(const bf16x8*)(wrow + (long)t * 16 * 128 + kt * 32);
            acc[t] = __builtin_amdgcn_mfma_f32_16x16x32_bf16(a, b, acc[t], 0, 0, 0);
        }
    }

    float as0 = asrc[l15], as1 = asrc[16 + l15];
    float ad0 = adst[l15], ad1 = adst[16 + l15];
#pragma unroll
    for (int t = 0; t < 2; ++t)
#pragma unroll
        for (int i = 0; i < 4; ++i)
            H2b[(long)(r0 + q * 4 + i) * 32 + t * 16 + l15] = f2bf(acc[t][i]);

#pragma unroll
    for (int i = 0; i < 4; ++i) {
        float ps = acc[0][i] * as0 + acc[1][i] * as1;
        float pd = acc[0][i] * ad0 + acc[1][i] * ad1;
#pragma unroll
        for (int m = 1; m < 16; m <<= 1) {
            ps += __shfl_xor(ps, m, 16);
            pd += __shfl_xor(pd, m, 16);
        }
        if (l15 == 0) {
            int r = r0 + q * 4 + i;
            ALS[r] = ps;
            ALD[r] = pd;
        }
    }
}

// ---------------- Edge aggregation (v1 structure, ALS4 interleave) ----------------
__global__ __launch_bounds__(256) void agg128(const unsigned short* __restrict__ Hb,
                                              const float* __restrict__ ALS4,
                                              const float* __restrict__ ALD4,
                                              const int* __restrict__ cnt,
                                              const unsigned short* __restrict__ psrc,
                                              const float* __restrict__ bias,
                                              unsigned short* __restrict__ OUTb) {
    int n = blockIdx.x * 4 + (threadIdx.x >> 6);
    n = __builtin_amdgcn_readfirstlane(n);
    if (n >= N_NODES) return;
    int lane = threadIdx.x & 63;
    int c = lane * 2;
    int head = lane >> 4;
    int e16 = lane & 15;
    float aldh = ALD4[n * 4 + head];
    int j0 = n << CAP_SHIFT;
    int j1 = j0 + __builtin_amdgcn_readfirstlane(cnt[n]);
    float a0 = 0.f, a1 = 0.f, dsum = 0.f;
    for (int jb = j0; jb < j1; jb += 16) {
        int j = jb + e16;
        int jc = (j < j1) ? j : (j1 - 1);
        int s = (int)psrc[jc];
        float e = ALS4[s * 4 + head] + aldh;
        e = (e > 0.f) ? e : 0.2f * e;
        float w = (j < j1) ? __expf(e) : 0.f;
        int st[16]; float wt[16];
#pragma unroll
        for (int t = 0; t < 16; ++t) {
            st[t] = __shfl(s, t, 16);
            wt[t] = __shfl(w, t, 16);
        }
        unsigned int hv[16];
#pragma unroll
        for (int t = 0; t < 16; ++t)
            hv[t] = *(const unsigned int*)(Hb + (long)st[t] * 128 + c);
#pragma unroll
        for (int t = 0; t < 16; ++t) {
            float h0 = bf2f((unsigned short)(hv[t] & 0xFFFF));
            float h1 = bf2f((unsigned short)(hv[t] >> 16));
            dsum += wt[t];
            a0 += wt[t] * h0;
            a1 += wt[t] * h1;
        }
    }
    float inv = 1.0f / dsum;
    float o0 = a0 * inv + bias[c];
    float o1 = a1 * inv + bias[c + 1];
    o0 = (o0 > 0.f) ? o0 : (__expf(o0) - 1.f);
    o1 = (o1 > 0.f) ? o1 : (__expf(o1) - 1.f);
    ushort2 ob; ob.x = f2bf(o0); ob.y = f2bf(o1);
    *(ushort2*)(OUTb + (long)n * 128 + c) = ob;
}

// 32-channel, 1-head; half-wave per node, padded buckets.
__global__ __launch_bounds__(256) void agg32(const unsigned short* __restrict__ H2b,
                                             const float* __restrict__ ALS,
                                             const float* __restrict__ ALD,
                                             const int* __restrict__ cnt,
                                             const unsigned short* __restrict__ psrc,
                                             const float* __restrict__ bias,
                                             float* __restrict__ OUT) {
    int wv = blockIdx.x * 4 + (threadIdx.x >> 6);
    int lane = threadIdx.x & 63;
    int col = lane & 31;
    int half = lane >> 5;
    int e16 = lane & 15;
    int n = wv * 2 + half;
    if (n >= N_NODES) return;
    float aldn = ALD[n];
    int j0 = n << CAP_SHIFT;
    int j1 = j0 + cnt[n];
    float a = 0.f, dsum = 0.f;
    for (int jb = j0; jb < j1; jb += 16) {
        int j = jb + e16;
        int jc = (j < j1) ? j : (j1 - 1);
        int s = (int)psrc[jc];
        float e = ALS[s] + aldn;
        e = (e > 0.f) ? e : 0.2f * e;
        float w = (j < j1) ? __expf(e) : 0.f;
        int st[16]; float wt[16];
#pragma unroll
        for (int t = 0; t < 16; ++t) {
            st[t] = __shfl(s, t, 16);
            wt[t] = __shfl(w, t, 16);
        }
        unsigned short hv[16];
#pragma unroll
        for (int t = 0; t < 16; ++t)
            hv[t] = H2b[st[t] * 32 + col];
#pragma unroll
        for (int t = 0; t < 16; ++t) {
            dsum += wt[t];
            a += wt[t] * bf2f(hv[t]);
        }
    }
    float o = a / dsum + bias[col];
    o = (o > 0.f) ? o : (__expf(o) - 1.f);
    OUT[n * 32 + col] = o;
}

// ---------------- Pooling + MLP ----------------
__global__ __launch_bounds__(256) void pool_kernel(const float* __restrict__ H3,
                                                   const int* __restrict__ batch,
                                                   float* __restrict__ gsum,
                                                   float* __restrict__ gcnt) {
    const int CHUNK = 40;
    int gid = (blockIdx.x * 256 + threadIdx.x) >> 5;
    int c = threadIdx.x & 31;
    int n0 = gid * CHUNK;
    if (n0 >= N_NODES) return;
    int n1 = n0 + CHUNK;
    if (n1 > N_NODES) n1 = N_NODES;
    int cur = batch[n0];
    float acc = 0.f;
    int cnt = 0;
    for (int n = n0; n < n1; ++n) {
        int b = batch[n];
        if (b != cur) {
            atomicAdd(&gsum[cur * 32 + c], acc);
            if (c == 0) atomicAdd(&gcnt[cur], (float)cnt);
            cur = b; acc = 0.f; cnt = 0;
        }
        acc += H3[n * 32 + c];
        cnt++;
    }
    atomicAdd(&gsum[cur * 32 + c], acc);
    if (c == 0) atomicAdd(&gcnt[cur], (float)cnt);
}

__global__ __launch_bounds__(256) void mlp_kernel(const float* __restrict__ gsum,
                                                  const float* __restrict__ gcnt,
                                                  const float* __restrict__ l1w,
                                                  const float* __restrict__ l1b,
                                                  const float* __restrict__ l2w,
                                                  const float* __restrict__ l2b,
                                                  float* __restrict__ out) {
    __shared__ float g[NUM_GRAPHS * 32];
    __shared__ float t1[NUM_GRAPHS * 128];
    int tid = threadIdx.x;
    for (int i = tid; i < NUM_GRAPHS * 32; i += 256) {
        float c = gcnt[i >> 5];
        g[i] = gsum[i] / fmaxf(c, 1.0f);
    }
    __syncthreads();
    for (int i = tid; i < NUM_GRAPHS * 128; i += 256) {
        int r = i >> 7, j = i & 127;
        float a = l1b[j];
        for (int k = 0; k < 32; ++k) a += g[r * 32 + k] * l1w[k * 128 + j];
        t1[i] = fmaxf(a, 0.f);
    }
    __syncthreads();
    for (int i = tid; i < NUM_GRAPHS * 8; i += 256) {
        int r = i >> 3, j = i & 7;
        float a = l2b[j];
        for (int k = 0; k < 128; ++k) a += t1[r * 128 + k] * l2w[k * 8 + j];
        out[i] = a;
    }
}

// ---------------- host ----------------

extern "C" void kernel_launch(void* const* d_in, const int* in_sizes, int n_in,
                              void* d_out, int out_size, void* d_ws, size_t ws_size,
                              hipStream_t stream) {
    const float* x      = (const float*)d_in[0];
    const int*   eidx   = (const int*)d_in[1];
    const int*   batch  = (const int*)d_in[2];
    const float* W0     = (const float*)d_in[3];
    const float* asrc0  = (const float*)d_in[4];
    const float* adst0  = (const float*)d_in[5];
    const float* b0     = (const float*)d_in[6];
    const float* W1     = (const float*)d_in[7];
    const float* asrc1  = (const float*)d_in[8];
    const float* adst1  = (const float*)d_in[9];
    const float* b1     = (const float*)d_in[10];
    const float* W2     = (const float*)d_in[11];
    const float* asrc2  = (const float*)d_in[12];
    const float* adst2  = (const float*)d_in[13];
    const float* b2     = (const float*)d_in[14];
    const float* l1w    = (const float*)d_in[15];
    const float* l1b    = (const float*)d_in[16];
    const float* l2w    = (const float*)d_in[17];
    const float* l2b    = (const float*)d_in[18];
    float* out = (float*)d_out;

    const int* esrc = eidx;
    const int* edst = eidx + N_EDGES;

    // workspace layout
    float* ALS  = (float*)d_ws;                       // N*4 (interleaved [N][4]; layer2 uses [N])
    float* ALD  = ALS + N_NODES * 4;                  // N*4
    float* h3   = ALD + N_NODES * 4;                  // N*32
    int* cnt    = (int*)(h3 + (long)N_NODES * 32);    // N (fully written by binB)
    int* bin_gcnt = cnt + N_NODES;                    // BINS   <- zero from here
    float* gsum = (float*)(bin_gcnt + BINS);          // 64*32
    float* gcnt = gsum + NUM_GRAPHS * 32;             // 64     <- zero to here
    unsigned int* bins = (unsigned int*)(gcnt + NUM_GRAPHS);     // BINS*BIN_CAP uint (3.2 MB)
    unsigned short* psrc = (unsigned short*)(bins + (long)BINS * BIN_CAP); // N*64 ushort (5.12 MB)
    uintptr_t p = (uintptr_t)(psrc + ((long)N_NODES << CAP_SHIFT));
    p = (p + 15) & ~(uintptr_t)15;
    unsigned short* Xb   = (unsigned short*)p;              // N*128 bf16
    unsigned short* Hb   = Xb + (long)N_NODES * 128;        // N*128 bf16
    unsigned short* OUTb = Hb + (long)N_NODES * 128;        // N*128 bf16
    unsigned short* H2b  = OUTb + (long)N_NODES * 128;      // N*32 bf16
    unsigned short* Wt0  = H2b + (long)N_NODES * 32;        // 128*128 bf16
    unsigned short* Wt1  = Wt0 + 128 * 128;                 // 128*128 bf16
    unsigned short* Wt2  = Wt1 + 128 * 128;                 // 32*128 bf16

    // zero bin_gcnt/gsum/gcnt (contiguous)
    size_t zbytes = (size_t)(BINS + NUM_GRAPHS * 32 + NUM_GRAPHS) * 4;
    hipMemsetAsync(bin_gcnt, 0, zbytes, stream);

    // merged: binA2 (counting-sort tiles) || cvt
    cvt_binA_kernel<<<A2BLKS + CVTX_BLOCKS + CVTW_BLOCKS, 256, 0, stream>>>(
        x, W0, W1, W2, Xb, Wt0, Wt1, Wt2, esrc, edst, bin_gcnt, bins);

    // merged: binB (bucket build via LDS tile) || gemm128 layer-0
    gemm0_binB_kernel<<<BINS + GEMM_BLOCKS, 256, 0, stream>>>(
        Xb, Wt0, asrc0, adst0, Hb, ALS, ALD, bin_gcnt, bins, cnt, psrc);
    agg128<<<10000, 256, 0, stream>>>(Hb, ALS, ALD, cnt, psrc, b0, OUTb);

    // layer 1
    gemm128_mfma<<<GEMM_BLOCKS, 256, 0, stream>>>(OUTb, Wt1, asrc1, adst1, Hb, ALS, ALD);
    agg128<<<10000, 256, 0, stream>>>(Hb, ALS, ALD, cnt, psrc, b1, OUTb);

    // layer 2
    gemm32_mfma<<<GEMM_BLOCKS, 256, 0, stream>>>(OUTb, Wt2, asrc2, adst2, H2b, ALS, ALD);
    agg32<<<5000, 256, 0, stream>>>(H2b, ALS, ALD, cnt, psrc, b2, h3);

    // pool + MLP
    pool_kernel<<<125, 256, 0, stream>>>(h3, batch, gsum, gcnt);
    mlp_kernel<<<1, 256, 0, stream>>>(gsum, gcnt, l1w, l1b, l2w, l2b, out);
}